// Round 9
// baseline (2831.315 us; speedup 1.0000x reference)
//
#include <hip/hip_runtime.h>
#include <stdint.h>

#define N_POINTS   400000
#define WIDTH      64
#define M_SAMPLES  1000          // N_POINTS / 400
#define NBLK       64
#define NTHR       512
#define NWAVE      (NTHR / 64)   // 8 waves per block
#define NTOT       (NBLK * NTHR) // 32768 threads -> 2 waves/SIMD on 64 CUs
#define PPT        13            // ceil(400000 / 32768)
#define TAIL_GID   (N_POINTS - (PPT - 1) * NTOT)  // gid < this => k=12 valid
#define EPAD       8             // entry stride = 64 B = ONE cache line, ONE writer
#define NREG       128           // region rotation; reuse distance 128
#define SLOT_WORDS (NREG * NBLK * EPAD)   // 65536 words = 512 KiB

// Entry (single 8-B word at the head of a PRIVATE 64-B line; ONE writer/line):
//   [63:32] dist f32 bits (non-negative -> monotone u32)
//   [26:19] tag = i & 255
//   [18:0]  N - idx (1..400000 < 2^19; ties -> lowest idx wins)
// Region r = (i-1) & 127. Stale entries are from i-128 (tag differs in bit 7);
// region r's first use is i = r+1 (tag != 0) so initial zeros never validate.
// Overwrite-before-gather impossible (R6/R7-verified skew argument).
// One-writer-per-line (R5: -575us) + 64-event narrow funnel (R5 vs R6) +
// wide compute (R7: -464us) all verified. This round touches ONLY the poll.

__global__ void fps_init(unsigned long long* slot, int* out) {
    int t = blockIdx.x * blockDim.x + threadIdx.x;
    if (t < SLOT_WORDS) slot[t] = 0ull;
    if (t == 0) out[0] = 0;      // seed index
}

// u64 max-reduce via DPP row-scan (HW-verified rounds 1/3/4/5/6/7).
// STAGES=3 + SRC=7  : max over lanes 0..7   (block-level, 8 wave maxima)
// STAGES=6 + SRC=63 : max over all 64 lanes
template <int STAGES, int SRCLANE>
__device__ inline unsigned long long wave_scan_max_u64(unsigned long long key) {
    unsigned int lo = (unsigned int)key;
    unsigned int hi = (unsigned int)(key >> 32);
#define FPS_DPP_STAGE(CTRL)                                                     \
    {                                                                           \
        unsigned int nlo = (unsigned int)__builtin_amdgcn_update_dpp(           \
            (int)lo, (int)lo, CTRL, 0xf, 0xf, false);                           \
        unsigned int nhi = (unsigned int)__builtin_amdgcn_update_dpp(           \
            (int)hi, (int)hi, CTRL, 0xf, 0xf, false);                           \
        unsigned long long cand = ((unsigned long long)nhi << 32) | nlo;        \
        unsigned long long cur  = ((unsigned long long)hi  << 32) | lo;         \
        if (cand > cur) { lo = nlo; hi = nhi; }                                 \
    }
    if constexpr (STAGES > 0) FPS_DPP_STAGE(0x111)  // row_shr:1
    if constexpr (STAGES > 1) FPS_DPP_STAGE(0x112)  // row_shr:2
    if constexpr (STAGES > 2) FPS_DPP_STAGE(0x114)  // row_shr:4
    if constexpr (STAGES > 3) FPS_DPP_STAGE(0x118)  // row_shr:8
    if constexpr (STAGES > 4) FPS_DPP_STAGE(0x142)  // row_bcast15
    if constexpr (STAGES > 5) FPS_DPP_STAGE(0x143)  // row_bcast31
#undef FPS_DPP_STAGE
    unsigned int rlo = (unsigned int)__builtin_amdgcn_readlane((int)lo, SRCLANE);
    unsigned int rhi = (unsigned int)__builtin_amdgcn_readlane((int)hi, SRCLANE);
    return ((unsigned long long)rhi << 32) | rlo;
}

// Workspace requirement: SLOT_WORDS * 8 B = 524,288 B in d_ws.
__global__ __launch_bounds__(NTHR)
void fps_main(const float* __restrict__ feats, int* __restrict__ out,
              unsigned long long* __restrict__ slot)
{
    const int tid  = threadIdx.x;
    const int bid  = blockIdx.x;
    const int lane = tid & 63;
    const int wid  = tid >> 6;
    const int gid  = bid * NTHR + tid;

    // Register-resident points + running min squared distance
    float px[PPT], py[PPT], pz[PPT], dd[PPT];
#pragma unroll
    for (int k = 0; k < PPT; k++) {
        int j = gid + k * NTOT;
        if (j < N_POINTS) {
            // row start is 256-B aligned -> one dwordx4 gets x,y,z(,w)
            float4 v = *reinterpret_cast<const float4*>(feats + (size_t)j * WIDTH);
            px[k] = v.x; py[k] = v.y; pz[k] = v.z;
        } else {
            px[k] = 0.f; py[k] = 0.f; pz[k] = 0.f;
        }
        dd[k] = 1e10f;          // matches jnp.full(..., 1e10, f32)
    }

    __shared__ unsigned long long s_wmax[NWAVE];
    __shared__ float s_qx, s_qy, s_qz;

    // Iteration-1 pivot = point 0 (bit-identical source values)
    float qx = feats[0];
    float qy = feats[1];
    float qz = feats[2];

    for (int i = 1; i < M_SAMPLES; i++) {
        const unsigned long long tg = (unsigned long long)(i & 255);
        unsigned long long* cur = slot + (size_t)((i - 1) & (NREG - 1)) * NBLK * EPAD;

        // ---- compute pass: update dd, float-track per-thread best (dist,idx) ----
        float bd = -1.0f;
        unsigned int bj = 0;
#pragma unroll
        for (int k = 0; k < PPT; k++) {
            int j = gid + k * NTOT;
            // IEEE ops in reference order; _rn intrinsics block fp-contract
            float dx = __fsub_rn(px[k], qx);
            float dy = __fsub_rn(py[k], qy);
            float dz = __fsub_rn(pz[k], qz);
            float d  = __fadd_rn(__fadd_rn(__fmul_rn(dx, dx), __fmul_rn(dy, dy)),
                                 __fmul_rn(dz, dz));
            float nd = fminf(dd[k], d);
            dd[k] = nd;
            // strict > keeps the smallest j on ties (j ascends with k)
            bool upd = (nd > bd);
            if (k == PPT - 1) upd = upd && (gid < TAIL_GID);
            bd = upd ? nd : bd;
            bj = upd ? (unsigned int)j : bj;
        }
        unsigned long long key =
            ((unsigned long long)__float_as_uint(bd) << 32) |
            (tg << 19) |
            (unsigned long long)(N_POINTS - bj);

        // ---- per-wave DPP reduce, stage into LDS ----
        unsigned long long wmax = wave_scan_max_u64<6, 63>(key);
        if (lane == 0) s_wmax[wid] = wmax;
        __syncthreads();

        if (wid == 0) {
            // ---- block reduce: 8 wave maxima -> ONE store to a private line ----
            unsigned long long bk = (lane < NWAVE) ? s_wmax[lane] : 0ull;
            unsigned long long blockmax = wave_scan_max_u64<3, 7>(bk);
            if (lane == 0)
                __hip_atomic_store(&cur[(size_t)bid * EPAD], blockmax,
                                   __ATOMIC_RELAXED, __HIP_MEMORY_SCOPE_AGENT);

            // ---- PIPELINED poll: lane l waits on block l's entry.
            //  * 3 loads in flight per lane -> request spacing ~L/3 instead of
            //    L (dependent spin), cutting mean detect delay ~L -> ~0.67L.
            //  * lane == bid short-circuits (it already holds blockmax).
            //  * the candidate-row fetch issues INSIDE the loop at the
            //    iteration a lane detects, so row-load latency overlaps the
            //    remaining lanes' polling instead of sitting on the tail.
            // Correctness: only a tag-matching word is accepted; exactly one
            // value with tag tg is ever written at this address (verified
            // protocol), so any-order / stale loads are harmless. Termination:
            // every block's store precedes its poll in program order, so all
            // 64 entries are eventually written regardless of timing.
            const unsigned long long* lp = cur + (size_t)lane * EPAD;
            unsigned long long e = blockmax;
            bool ok = (lane == bid);
            unsigned long long a = 0, b = 0, c = 0;
            if (!ok) {
                a = __hip_atomic_load(lp, __ATOMIC_RELAXED, __HIP_MEMORY_SCOPE_AGENT);
                b = __hip_atomic_load(lp, __ATOMIC_RELAXED, __HIP_MEMORY_SCOPE_AGENT);
                c = __hip_atomic_load(lp, __ATOMIC_RELAXED, __HIP_MEMORY_SCOPE_AGENT);
            }
            unsigned int widx = 0;
            float4 pv = make_float4(0.f, 0.f, 0.f, 0.f);
            if (ok) {   // self-lane: issue its row fetch immediately
                widx = N_POINTS - (unsigned int)(e & 0x7FFFFull);
                pv = *reinterpret_cast<const float4*>(feats + (size_t)widx * WIDTH);
            }
            while (__any(!ok)) {
                if (!ok) {
                    if (((a >> 19) & 255ull) == tg) {
                        e = a; ok = true;
                        widx = N_POINTS - (unsigned int)(e & 0x7FFFFull);
                        pv = *reinterpret_cast<const float4*>(feats + (size_t)widx * WIDTH);
                    } else {
                        a = b; b = c;
                        c = __hip_atomic_load(lp, __ATOMIC_RELAXED,
                                              __HIP_MEMORY_SCOPE_AGENT);
                    }
                }
            }

            unsigned long long win = wave_scan_max_u64<6, 63>(e);

            // Exactly one lane matches (entry indices are globally distinct)
            if (e == win) {
                s_qx = pv.x; s_qy = pv.y; s_qz = pv.z;
                if (bid == 0) out[i] = (int)widx;
            }
        }
        // Waves 1..7 wait here while wave 0 runs the exchange
        __syncthreads();
        qx = s_qx; qy = s_qy; qz = s_qz;
    }
}

extern "C" void kernel_launch(void* const* d_in, const int* in_sizes, int n_in,
                              void* d_out, int out_size, void* d_ws, size_t ws_size,
                              hipStream_t stream) {
    const float* feats = (const float*)d_in[0];
    int* out = (int*)d_out;
    unsigned long long* slot = (unsigned long long*)d_ws;  // 512 KiB used

    fps_init<<<(SLOT_WORDS + 255) / 256, 256, 0, stream>>>(slot, out);
    // 64 blocks x 512 thr: all blocks trivially co-resident
    fps_main<<<NBLK, NTHR, 0, stream>>>(feats, out, slot);
}

// Round 10
// 2423.302 us; speedup vs baseline: 1.1684x; 1.1684x over previous
//
#include <hip/hip_runtime.h>
#include <stdint.h>

#define N_POINTS   400000
#define WIDTH      64
#define M_SAMPLES  1000          // N_POINTS / 400
#define NBLK       64
#define NTHR       512
#define NWAVE      (NTHR / 64)   // 8 waves per block
#define NTOT       (NBLK * NTHR) // 32768 threads -> 2 waves/SIMD on 64 CUs
#define PPT        13            // ceil(400000 / 32768)
#define TAIL_GID   (N_POINTS - (PPT - 1) * NTOT)  // gid < this => k=12 valid
#define EPAD       8             // entry stride = 64 B = ONE cache line, ONE writer
#define NREG       128           // region rotation; reuse distance 128
#define SLOT_WORDS (NREG * NBLK * EPAD)   // 65536 words = 512 KiB

// Entry (single 8-B word at the head of a PRIVATE 64-B line; ONE writer/line):
//   [63:32] dist f32 bits (non-negative -> monotone u32)
//   [26:19] tag = i & 255
//   [18:0]  N - idx (1..400000 < 2^19; ties -> lowest idx wins)
// Region r = (i-1) & 127. Stale entries are from i-128 (tag differs in bit 7);
// region r's first use is i = r+1 (tag != 0) so initial zeros never validate.
// Overwrite-before-gather impossible (R6/R7-verified skew argument).
// Verified structure (R7, 2131 us): one-writer-per-line + 64-event narrow
// funnel + wide compute + dependent-spin poll. THIS round changes ONLY the
// poll: clean 3-deep software pipeline (rotation + tag check, nothing else in
// the loop -- R9 showed a divergent in-loop fetch forces conservative vmcnt
// drains and regresses 600us).

__global__ void fps_init(unsigned long long* slot, int* out) {
    int t = blockIdx.x * blockDim.x + threadIdx.x;
    if (t < SLOT_WORDS) slot[t] = 0ull;
    if (t == 0) out[0] = 0;      // seed index
}

// u64 max-reduce via DPP row-scan (HW-verified rounds 1/3/4/5/6/7/9).
// STAGES=3 + SRC=7  : max over lanes 0..7   (block-level, 8 wave maxima)
// STAGES=6 + SRC=63 : max over all 64 lanes
template <int STAGES, int SRCLANE>
__device__ inline unsigned long long wave_scan_max_u64(unsigned long long key) {
    unsigned int lo = (unsigned int)key;
    unsigned int hi = (unsigned int)(key >> 32);
#define FPS_DPP_STAGE(CTRL)                                                     \
    {                                                                           \
        unsigned int nlo = (unsigned int)__builtin_amdgcn_update_dpp(           \
            (int)lo, (int)lo, CTRL, 0xf, 0xf, false);                           \
        unsigned int nhi = (unsigned int)__builtin_amdgcn_update_dpp(           \
            (int)hi, (int)hi, CTRL, 0xf, 0xf, false);                           \
        unsigned long long cand = ((unsigned long long)nhi << 32) | nlo;        \
        unsigned long long cur  = ((unsigned long long)hi  << 32) | lo;         \
        if (cand > cur) { lo = nlo; hi = nhi; }                                 \
    }
    if constexpr (STAGES > 0) FPS_DPP_STAGE(0x111)  // row_shr:1
    if constexpr (STAGES > 1) FPS_DPP_STAGE(0x112)  // row_shr:2
    if constexpr (STAGES > 2) FPS_DPP_STAGE(0x114)  // row_shr:4
    if constexpr (STAGES > 3) FPS_DPP_STAGE(0x118)  // row_shr:8
    if constexpr (STAGES > 4) FPS_DPP_STAGE(0x142)  // row_bcast15
    if constexpr (STAGES > 5) FPS_DPP_STAGE(0x143)  // row_bcast31
#undef FPS_DPP_STAGE
    unsigned int rlo = (unsigned int)__builtin_amdgcn_readlane((int)lo, SRCLANE);
    unsigned int rhi = (unsigned int)__builtin_amdgcn_readlane((int)hi, SRCLANE);
    return ((unsigned long long)rhi << 32) | rlo;
}

// Workspace requirement: SLOT_WORDS * 8 B = 524,288 B in d_ws.
__global__ __launch_bounds__(NTHR)
void fps_main(const float* __restrict__ feats, int* __restrict__ out,
              unsigned long long* __restrict__ slot)
{
    const int tid  = threadIdx.x;
    const int bid  = blockIdx.x;
    const int lane = tid & 63;
    const int wid  = tid >> 6;
    const int gid  = bid * NTHR + tid;

    // Register-resident points + running min squared distance
    float px[PPT], py[PPT], pz[PPT], dd[PPT];
#pragma unroll
    for (int k = 0; k < PPT; k++) {
        int j = gid + k * NTOT;
        if (j < N_POINTS) {
            // row start is 256-B aligned -> one dwordx4 gets x,y,z(,w)
            float4 v = *reinterpret_cast<const float4*>(feats + (size_t)j * WIDTH);
            px[k] = v.x; py[k] = v.y; pz[k] = v.z;
        } else {
            px[k] = 0.f; py[k] = 0.f; pz[k] = 0.f;
        }
        dd[k] = 1e10f;          // matches jnp.full(..., 1e10, f32)
    }

    __shared__ unsigned long long s_wmax[NWAVE];
    __shared__ float s_qx, s_qy, s_qz;

    // Iteration-1 pivot = point 0 (bit-identical source values)
    float qx = feats[0];
    float qy = feats[1];
    float qz = feats[2];

    for (int i = 1; i < M_SAMPLES; i++) {
        const unsigned long long tg = (unsigned long long)(i & 255);
        unsigned long long* cur = slot + (size_t)((i - 1) & (NREG - 1)) * NBLK * EPAD;

        // ---- compute pass: update dd, float-track per-thread best (dist,idx) ----
        float bd = -1.0f;
        unsigned int bj = 0;
#pragma unroll
        for (int k = 0; k < PPT; k++) {
            int j = gid + k * NTOT;
            // IEEE ops in reference order; _rn intrinsics block fp-contract
            float dx = __fsub_rn(px[k], qx);
            float dy = __fsub_rn(py[k], qy);
            float dz = __fsub_rn(pz[k], qz);
            float d  = __fadd_rn(__fadd_rn(__fmul_rn(dx, dx), __fmul_rn(dy, dy)),
                                 __fmul_rn(dz, dz));
            float nd = fminf(dd[k], d);
            dd[k] = nd;
            // strict > keeps the smallest j on ties (j ascends with k)
            bool upd = (nd > bd);
            if (k == PPT - 1) upd = upd && (gid < TAIL_GID);
            bd = upd ? nd : bd;
            bj = upd ? (unsigned int)j : bj;
        }
        unsigned long long key =
            ((unsigned long long)__float_as_uint(bd) << 32) |
            (tg << 19) |
            (unsigned long long)(N_POINTS - bj);

        // ---- per-wave DPP reduce, stage into LDS ----
        unsigned long long wmax = wave_scan_max_u64<6, 63>(key);
        if (lane == 0) s_wmax[wid] = wmax;
        __syncthreads();

        if (wid == 0) {
            // ---- block reduce: 8 wave maxima -> ONE store to a private line ----
            unsigned long long bk = (lane < NWAVE) ? s_wmax[lane] : 0ull;
            unsigned long long blockmax = wave_scan_max_u64<3, 7>(bk);
            if (lane == 0)
                __hip_atomic_store(&cur[(size_t)bid * EPAD], blockmax,
                                   __ATOMIC_RELAXED, __HIP_MEMORY_SCOPE_AGENT);

            // ---- 3-deep PIPELINED poll: lane l waits on block l's entry.
            // Rotation keeps 3 loads in flight -> request spacing ~L/3 and
            // detection ~0.67L past visibility (vs ~L for a dependent spin).
            // Loop body is UNIFORM (rotation + tag check only; no other
            // memory ops) so the compiler can emit a static vmcnt(2) -- the
            // R9 regression came from a divergent in-loop fetch breaking
            // this. Correctness: only a tag-tg word is ever accepted, and
            // exactly one tag-tg value is ever written at this address;
            // stale/reordered loads just fail the check and retry.
            const unsigned long long* lp = cur + (size_t)lane * EPAD;
            unsigned long long a, b, c, e;
            a = __hip_atomic_load(lp, __ATOMIC_RELAXED, __HIP_MEMORY_SCOPE_AGENT);
            b = __hip_atomic_load(lp, __ATOMIC_RELAXED, __HIP_MEMORY_SCOPE_AGENT);
            c = __hip_atomic_load(lp, __ATOMIC_RELAXED, __HIP_MEMORY_SCOPE_AGENT);
            for (;;) {
                if (((a >> 19) & 255ull) == tg) { e = a; break; }
                a = b; b = c;
                c = __hip_atomic_load(lp, __ATOMIC_RELAXED,
                                      __HIP_MEMORY_SCOPE_AGENT);
            }

            // ---- speculative pivot fetch (AFTER the loop, R7-verified):
            //      each lane fetches ITS candidate's row; latency overlaps
            //      the final DPP reduce ----
            unsigned int widx = N_POINTS - (unsigned int)(e & 0x7FFFFull);
            float4 pv = *reinterpret_cast<const float4*>(feats + (size_t)widx * WIDTH);

            unsigned long long win = wave_scan_max_u64<6, 63>(e);

            // Exactly one lane matches (entry indices are globally distinct)
            if (e == win) {
                s_qx = pv.x; s_qy = pv.y; s_qz = pv.z;
                if (bid == 0) out[i] = (int)widx;
            }
        }
        // Waves 1..7 wait here while wave 0 runs the exchange
        __syncthreads();
        qx = s_qx; qy = s_qy; qz = s_qz;
    }
}

extern "C" void kernel_launch(void* const* d_in, const int* in_sizes, int n_in,
                              void* d_out, int out_size, void* d_ws, size_t ws_size,
                              hipStream_t stream) {
    const float* feats = (const float*)d_in[0];
    int* out = (int*)d_out;
    unsigned long long* slot = (unsigned long long*)d_ws;  // 512 KiB used

    fps_init<<<(SLOT_WORDS + 255) / 256, 256, 0, stream>>>(slot, out);
    // 64 blocks x 512 thr: all blocks trivially co-resident
    fps_main<<<NBLK, NTHR, 0, stream>>>(feats, out, slot);
}